// Round 3
// baseline (516.670 us; speedup 1.0000x reference)
//
#include <hip/hip_runtime.h>

#define DIN 150528
#define DD 512
#define NC 100
#define NM 64
#define NFEAT 256
#define EPSF 1e-6f
#define KSTEPS (DIN / 32) /* 4704 */

typedef float f32x4 __attribute__((ext_vector_type(4)));
typedef float f32x2 __attribute__((ext_vector_type(2)));
typedef __bf16 bf16x8 __attribute__((ext_vector_type(8)));
typedef unsigned short u16x8 __attribute__((ext_vector_type(8)));

static __device__ __forceinline__ unsigned short f2bf(float x) {
  unsigned int u = __builtin_bit_cast(unsigned int, x);
  u += 0x7FFFu + ((u >> 16) & 1u);  // RNE
  return (unsigned short)(u >> 16);
}
static __device__ __forceinline__ float bf2f(unsigned short h) {
  return __builtin_bit_cast(float, ((unsigned int)h) << 16);
}

// ---------------------------------------------------------------------------
// Kernel 1: f_part[s] = image @ W_enc (k-slice s), split-K over 256 blocks.
// Partials stored as bf16 (halves partial-buffer HBM traffic vs fp32; error
// ~1.5e-4 abs on f, negligible vs bf16-input rounding).
// Block: 256 threads = 4 waves; wave w owns N-range [w*128, w*128+128).
// No LDS: W fragments direct-from-global (4x64B segments/inst), A via float4.
// MFMA 16x16x32 bf16: A[m=lane&15][k=quad*8+j], B[k=quad*8+j][n=lane&15],
// C: col=lane&15, row=quad*4+reg (learn_hip m89-verified layouts).
// ---------------------------------------------------------------------------
__global__ __launch_bounds__(256, 1) void gemm_f(
    const float* __restrict__ image, const float* __restrict__ W,
    unsigned short* __restrict__ f_part) {
  const int tid = threadIdx.x;
  const int wv = tid >> 6;
  const int lane = tid & 63;
  const int q = lane >> 4;
  const int r16 = lane & 15;
  const int nb = wv * 128;

  f32x4 acc[4][8];
#pragma unroll
  for (int mt = 0; mt < 4; ++mt)
#pragma unroll
    for (int nt = 0; nt < 8; ++nt)
#pragma unroll
      for (int r = 0; r < 4; ++r) acc[mt][nt][r] = 0.0f;

  const int b = blockIdx.x;                 // grid must be 256
  const int s0 = (b * KSTEPS) >> 8;
  const int s1 = ((b + 1) * KSTEPS) >> 8;

  for (int s = s0; s < s1; ++s) {
    const int k0 = s * 32;
    f32x4 alo[4], ahi[4];
#pragma unroll
    for (int mt = 0; mt < 4; ++mt) {
      const float* ap = image + (size_t)(mt * 16 + r16) * DIN + (k0 + q * 8);
      alo[mt] = *(const f32x4*)ap;
      ahi[mt] = *(const f32x4*)(ap + 4);
    }
    float wr[8][8];
#pragma unroll
    for (int nt = 0; nt < 8; ++nt) {
      const float* wp = W + (size_t)(k0 + q * 8) * DD + (nb + nt * 16 + r16);
#pragma unroll
      for (int j = 0; j < 8; ++j) wr[nt][j] = wp[(size_t)j * DD];
    }
    bf16x8 av[4];
#pragma unroll
    for (int mt = 0; mt < 4; ++mt) {
      u16x8 u;
      u[0] = f2bf(alo[mt][0]); u[1] = f2bf(alo[mt][1]);
      u[2] = f2bf(alo[mt][2]); u[3] = f2bf(alo[mt][3]);
      u[4] = f2bf(ahi[mt][0]); u[5] = f2bf(ahi[mt][1]);
      u[6] = f2bf(ahi[mt][2]); u[7] = f2bf(ahi[mt][3]);
      av[mt] = __builtin_bit_cast(bf16x8, u);
    }
    bf16x8 bv[8];
#pragma unroll
    for (int nt = 0; nt < 8; ++nt) {
      u16x8 u;
#pragma unroll
      for (int j = 0; j < 8; ++j) u[j] = f2bf(wr[nt][j]);
      bv[nt] = __builtin_bit_cast(bf16x8, u);
    }
#pragma unroll
    for (int mt = 0; mt < 4; ++mt)
#pragma unroll
      for (int nt = 0; nt < 8; ++nt)
        acc[mt][nt] = __builtin_amdgcn_mfma_f32_16x16x32_bf16(
            av[mt], bv[nt], acc[mt][nt], 0, 0, 0);
  }

  unsigned short* outp = f_part + (size_t)b * (NM * DD);
#pragma unroll
  for (int mt = 0; mt < 4; ++mt)
#pragma unroll
    for (int nt = 0; nt < 8; ++nt) {
      const int n = nb + nt * 16 + r16;
#pragma unroll
      for (int r = 0; r < 4; ++r) {
        const int m = mt * 16 + q * 4 + r;
        outp[m * DD + n] = f2bf(acc[mt][nt][r]);
      }
    }
}

// ---------------------------------------------------------------------------
// Kernel 2: fused reduce + normalize. Grid 64 (one m-row each) x 256 threads.
// Thread t owns cols {2t, 2t+1} via one packed-u32 load per split-K slice
// (1 KB/slice/block, coalesced). Then block-wide sum-of-squares -> rsqrt ->
// fn (fp32).
// ---------------------------------------------------------------------------
__global__ __launch_bounds__(256) void reduce_norm(
    const unsigned short* __restrict__ f_part, float* __restrict__ fn) {
  const int m = blockIdx.x;
  const int t = threadIdx.x;
  const unsigned int* p =
      (const unsigned int*)f_part + (size_t)m * 256 + t;
  float s0 = 0.0f, s1 = 0.0f;
#pragma unroll 16
  for (int s = 0; s < 256; ++s) {
    const unsigned int v = p[(size_t)s * (NM * DD / 2)];
    s0 += bf2f((unsigned short)(v & 0xFFFFu));
    s1 += bf2f((unsigned short)(v >> 16));
  }
  float ss = s0 * s0 + s1 * s1;
#pragma unroll
  for (int o = 32; o; o >>= 1) ss += __shfl_xor(ss, o);
  __shared__ float red[4];
  if ((t & 63) == 0) red[t >> 6] = ss;
  __syncthreads();
  const float inv = 1.0f / sqrtf(red[0] + red[1] + red[2] + red[3]);
  f32x2 o2;
  o2[0] = s0 * inv;
  o2[1] = s1 * inv;
  *(f32x2*)(fn + m * DD + 2 * t) = o2;
}

// ---------------------------------------------------------------------------
// Kernel 3 (fused wk + final): per class c:
//  Phase 1: gather keys_sel (64x256) & text_sel (100x256) -> bf16 LDS,
//   L = keys_sel @ text_sel^T via bf16 MFMA (M=64,N=112pad,K=256 in 2 halves),
//   softmax over j2, p_cc -> w[m], kw[j] = sum_m w[m]*keys_sel[m][j] (LDS).
//  Phase 2: out[b][c] = alpha*exp(beta*cache-beta) + exp(ls)*dot(fn_b,text_c),
//   cache = (1/64) sum_j fn[b][idx[c][j]] * kw[j]; wave wv owns b=wv,wv+4,...
// ---------------------------------------------------------------------------
__global__ __launch_bounds__(256) void wk_final(
    const float* __restrict__ text, const float* __restrict__ keys,
    const int* __restrict__ indices, const float* __restrict__ pgamma,
    const float* __restrict__ fn, const float* __restrict__ pls,
    const float* __restrict__ palpha, const float* __restrict__ pbeta,
    float* __restrict__ out) {
  const int c = blockIdx.x;
  const int t = threadIdx.x;
  const int wv = t >> 6, lane = t & 63;
  const int q = lane >> 4, r16 = lane & 15;

  __shared__ __align__(16) unsigned short A_lds[64 * 264];   // 33792 B, full K
  __shared__ __align__(16) unsigned short B_lds[112 * 136];  // 30464 B, K-half
  __shared__ __align__(16) int idx_s[256];                   // 1024 B

  idx_s[t] = indices[c * 256 + t];
  __syncthreads();

  // Gather A (keys_sel) full K, bf16. thread t = column j.
  {
    const int j = t;
    const float* kp = keys + (size_t)c * 64 * 512 + idx_s[j];
#pragma unroll 8
    for (int m = 0; m < 64; ++m) A_lds[m * 264 + j] = f2bf(kp[(size_t)m * 512]);
  }

  f32x4 acc[7];
#pragma unroll
  for (int nt = 0; nt < 7; ++nt)
#pragma unroll
    for (int r = 0; r < 4; ++r) acc[nt][r] = 0.0f;
  const int mt = wv;

  for (int kh = 0; kh < 2; ++kh) {
    __syncthreads();  // previous B reads (or A writes) complete
    {
      const int kk = t & 127;
      const float* tp = text + idx_s[kh * 128 + kk];
      for (int n = (t >> 7); n < 112; n += 2)
        B_lds[n * 136 + kk] =
            (n < NC) ? f2bf(tp[(size_t)n * 512]) : (unsigned short)0;
    }
    __syncthreads();
#pragma unroll
    for (int ks = 0; ks < 4; ++ks) {
      bf16x8 afr = *(const bf16x8*)(A_lds + (mt * 16 + r16) * 264 + kh * 128 +
                                    ks * 32 + q * 8);
#pragma unroll
      for (int nt = 0; nt < 7; ++nt) {
        bf16x8 bfr =
            *(const bf16x8*)(B_lds + (nt * 16 + r16) * 136 + ks * 32 + q * 8);
        acc[nt] = __builtin_amdgcn_mfma_f32_16x16x32_bf16(afr, bfr, acc[nt],
                                                          0, 0, 0);
      }
    }
  }
  __syncthreads();

  // C (64x113 fp32 = 28928 B) overlays B_lds (30464 B).
  float* C_lds = reinterpret_cast<float*>(B_lds);
#pragma unroll
  for (int nt = 0; nt < 7; ++nt) {
    const int j2 = nt * 16 + r16;
#pragma unroll
    for (int r = 0; r < 4; ++r) {
      const int m = mt * 16 + q * 4 + r;
      C_lds[m * 113 + j2] = acc[nt][r];
    }
  }
  __syncthreads();

  float* w_lds = reinterpret_cast<float*>(idx_s);  // idx reloadable from L2
  if (t < 64) {
    const int m = t;
    float mx = -1e30f;
    for (int j2 = 0; j2 < NC; ++j2) mx = fmaxf(mx, C_lds[m * 113 + j2]);
    float sum = 0.0f;
    for (int j2 = 0; j2 < NC; ++j2) sum += expf(C_lds[m * 113 + j2] - mx);
    const float p = expf(C_lds[m * 113 + c] - mx) / sum;
    const float KL = log2f((1.0f + EPSF) / (p + EPSF));
    w_lds[m] = expf(KL * (*pgamma));
  }
  __syncthreads();

  // kw[j] into LDS (overlay dead C region — C consumed above).
  float* kw_lds = C_lds;
  {
    const int j = t;
    float kwv = 0.0f;
#pragma unroll 8
    for (int m = 0; m < 64; ++m) kwv += w_lds[m] * bf2f(A_lds[m * 264 + j]);
    kw_lds[j] = kwv;
  }
  __syncthreads();

  // Phase 2: final. Barrier-free per-wave b-loop, shuffle reductions.
  int idx4[4];
  float kw4[4];
#pragma unroll
  for (int i = 0; i < 4; ++i) {
    idx4[i] = indices[c * 256 + i * 64 + lane];  // L2-hit reload
    kw4[i] = kw_lds[i * 64 + lane];
  }
  float tc[8];
#pragma unroll
  for (int i = 0; i < 8; ++i) tc[i] = text[c * 512 + i * 64 + lane];
  const float ls = expf(*pls);
  const float alpha = *palpha, beta = *pbeta;

  for (int b = wv; b < 64; b += 4) {
    const float* fr = fn + b * DD;
    float cp = 0.0f, lp = 0.0f;
#pragma unroll
    for (int i = 0; i < 4; ++i) cp += fr[idx4[i]] * kw4[i];
#pragma unroll
    for (int i = 0; i < 8; ++i) lp += fr[i * 64 + lane] * tc[i];
#pragma unroll
    for (int o = 32; o; o >>= 1) {
      cp += __shfl_xor(cp, o);
      lp += __shfl_xor(lp, o);
    }
    if (lane == 0)
      out[b * NC + c] =
          alpha * expf(beta * (cp * (1.0f / 64.0f)) - beta) + ls * lp;
  }
}

// ---------------------------------------------------------------------------
extern "C" void kernel_launch(void* const* d_in, const int* in_sizes, int n_in,
                              void* d_out, int out_size, void* d_ws,
                              size_t ws_size, hipStream_t stream) {
  const float* image = (const float*)d_in[0];
  const float* W = (const float*)d_in[1];
  const float* text = (const float*)d_in[2];
  const float* keys = (const float*)d_in[3];
  const float* pls = (const float*)d_in[4];
  const int* idx = (const int*)d_in[5];
  const float* palpha = (const float*)d_in[6];
  const float* pbeta = (const float*)d_in[7];
  const float* pgamma = (const float*)d_in[8];
  float* out = (float*)d_out;

  char* ws = (char*)d_ws;
  unsigned short* f_part = (unsigned short*)ws;  // 256*64*512*2 = 16777216 B
  float* fn = (float*)(ws + 16777216);           // 64*512*4     = 131072 B

  gemm_f<<<256, 256, 0, stream>>>(image, W, f_part);
  reduce_norm<<<64, 256, 0, stream>>>(f_part, fn);
  wk_final<<<NC, 256, 0, stream>>>(text, keys, idx, pgamma, fn, pls, palpha,
                                   pbeta, out);
}